// Round 1
// baseline (507.977 us; speedup 1.0000x reference)
//
#include <hip/hip_runtime.h>
#include <math.h>

#define N_NODES 50000
#define N_EDGES 800000
#define IN_F 128
#define HID 64

// ---------------------------------------------------------------------------
// deg_out[src[e]] += 1 ; deg_in[dst[e]] += 1
__global__ void degrees_kernel(const int* __restrict__ src, const int* __restrict__ dst,
                               float* __restrict__ deg_out, float* __restrict__ deg_in) {
    int e = blockIdx.x * blockDim.x + threadIdx.x;
    if (e < N_EDGES) {
        atomicAdd(&deg_out[src[e]], 1.0f);
        atomicAdd(&deg_in[dst[e]], 1.0f);
    }
}

// norm = clip(deg,1,inf)^-0.5
__global__ void norms_kernel(const float* __restrict__ deg_out, const float* __restrict__ deg_in,
                             float* __restrict__ nsrc, float* __restrict__ ndst) {
    int i = blockIdx.x * blockDim.x + threadIdx.x;
    if (i < N_NODES) {
        nsrc[i] = 1.0f / sqrtf(fmaxf(deg_out[i], 1.0f));
        ndst[i] = 1.0f / sqrtf(fmaxf(deg_in[i], 1.0f));
    }
}

// y1 = (x @ W1) * nsrc[:,None]   -- wave per row, lane = output feature.
// W1 (128x64, 32KB) staged in LDS; x row broadcast via readlane shuffles.
__global__ void gemm1_kernel(const float* __restrict__ x, const float* __restrict__ W1,
                             const float* __restrict__ nsrc, float* __restrict__ y1) {
    __shared__ float w[IN_F * HID];
    for (int t = threadIdx.x; t < IN_F * HID; t += blockDim.x) w[t] = W1[t];
    __syncthreads();

    int lane = threadIdx.x & 63;
    int wave = threadIdx.x >> 6;
    int wid  = blockIdx.x * (blockDim.x >> 6) + wave;
    int nw   = gridDim.x * (blockDim.x >> 6);

    for (int row = wid; row < N_NODES; row += nw) {
        float xa = x[row * IN_F + lane];        // cols 0..63
        float xb = x[row * IN_F + 64 + lane];   // cols 64..127
        float acc = 0.0f;
        #pragma unroll
        for (int k = 0; k < 64; ++k) {
            acc = fmaf(__shfl(xa, k, 64), w[k * HID + lane], acc);
            acc = fmaf(__shfl(xb, k, 64), w[(64 + k) * HID + lane], acc);
        }
        y1[row * HID + lane] = acc * nsrc[row];
    }
}

// agg1[dst[e]][:] += y1[src[e]][:]   -- wave per edge, lane = feature.
__global__ void agg1_kernel(const int* __restrict__ src, const int* __restrict__ dst,
                            const float* __restrict__ y1, float* __restrict__ agg1) {
    int lane = threadIdx.x & 63;
    int wid  = (blockIdx.x * blockDim.x + threadIdx.x) >> 6;
    int nw   = (gridDim.x * blockDim.x) >> 6;
    for (int e = wid; e < N_EDGES; e += nw) {
        int s = src[e], d = dst[e];
        atomicAdd(&agg1[d * HID + lane], y1[s * HID + lane]);
    }
}

// h1 = relu(agg1*ndst + b1) * drop ;  s = (h1 . W2) * nsrc   -- wave per node.
__global__ void h1s_kernel(const float* __restrict__ agg1, const float* __restrict__ ndst,
                           const float* __restrict__ nsrc, const float* __restrict__ b1,
                           const float* __restrict__ drop, const float* __restrict__ W2,
                           float* __restrict__ s) {
    int lane = threadIdx.x & 63;
    int wid  = (blockIdx.x * blockDim.x + threadIdx.x) >> 6;
    int nw   = (gridDim.x * blockDim.x) >> 6;
    for (int i = wid; i < N_NODES; i += nw) {
        float a = agg1[i * HID + lane] * ndst[i] + b1[lane];
        a = fmaxf(a, 0.0f) * drop[i * HID + lane];
        float c = a * W2[lane];
        #pragma unroll
        for (int m = 32; m >= 1; m >>= 1) c += __shfl_xor(c, m, 64);
        if (lane == 0) s[i] = c * nsrc[i];
    }
}

// agg2[dst[e]] += s[src[e]]   -- scalar per edge.
__global__ void agg2_kernel(const int* __restrict__ src, const int* __restrict__ dst,
                            const float* __restrict__ s, float* __restrict__ agg2) {
    int e = blockIdx.x * blockDim.x + threadIdx.x;
    if (e < N_EDGES) atomicAdd(&agg2[dst[e]], s[src[e]]);
}

// out = sigmoid(agg2*ndst + b2)
__global__ void final_kernel(const float* __restrict__ agg2, const float* __restrict__ ndst,
                             const float* __restrict__ b2, float* __restrict__ out) {
    int i = blockIdx.x * blockDim.x + threadIdx.x;
    if (i < N_NODES) {
        float v = agg2[i] * ndst[i] + b2[0];
        out[i] = 1.0f / (1.0f + expf(-v));
    }
}

extern "C" void kernel_launch(void* const* d_in, const int* in_sizes, int n_in,
                              void* d_out, int out_size, void* d_ws, size_t ws_size,
                              hipStream_t stream) {
    const float* x    = (const float*)d_in[0];
    const float* W1   = (const float*)d_in[1];
    const float* b1   = (const float*)d_in[2];
    const float* W2   = (const float*)d_in[3];
    const float* b2   = (const float*)d_in[4];
    const int*   src  = (const int*)d_in[5];
    const int*   dst  = (const int*)d_in[6];
    const float* drop = (const float*)d_in[7];
    float* out = (float*)d_out;

    // Workspace layout (floats). Big 256B-aligned arrays first.
    float* ws      = (float*)d_ws;
    float* agg1    = ws;                         // 64N (zeroed)
    float* y1      = ws + (size_t)64 * N_NODES;  // 64N
    float* deg_out = ws + (size_t)128 * N_NODES; // N  (zeroed)
    float* deg_in  = deg_out + N_NODES;          // N  (zeroed)
    float* agg2    = deg_in + N_NODES;           // N  (zeroed)
    float* nsrc    = agg2 + N_NODES;             // N
    float* ndst    = nsrc + N_NODES;             // N
    float* s       = ndst + N_NODES;             // N
    // total: 134N floats = 26.8 MB

    hipMemsetAsync(agg1, 0, (size_t)64 * N_NODES * sizeof(float), stream);
    hipMemsetAsync(deg_out, 0, (size_t)3 * N_NODES * sizeof(float), stream);

    degrees_kernel<<<(N_EDGES + 255) / 256, 256, 0, stream>>>(src, dst, deg_out, deg_in);
    norms_kernel<<<(N_NODES + 255) / 256, 256, 0, stream>>>(deg_out, deg_in, nsrc, ndst);
    gemm1_kernel<<<2048, 256, 0, stream>>>(x, W1, nsrc, y1);
    agg1_kernel<<<12800, 256, 0, stream>>>(src, dst, y1, agg1);
    h1s_kernel<<<4096, 256, 0, stream>>>(agg1, ndst, nsrc, b1, drop, W2, s);
    agg2_kernel<<<(N_EDGES + 255) / 256, 256, 0, stream>>>(src, dst, s, agg2);
    final_kernel<<<(N_NODES + 255) / 256, 256, 0, stream>>>(agg2, ndst, b2, out);
}

// Round 2
// 302.343 us; speedup vs baseline: 1.6801x; 1.6801x over previous
//
#include <hip/hip_runtime.h>
#include <math.h>

#define N_NODES 50000
#define N_EDGES 800000
#define IN_F 128
#define HID 64
#define NB_SCAN ((N_NODES + 255) / 256)   // 196 scan blocks

// ---------------------------------------------------------------------------
// int histograms: cnt_src = out-degree, cnt_dst = in-degree
__global__ void hist_kernel(const int* __restrict__ src, const int* __restrict__ dst,
                            int* __restrict__ cnt_src, int* __restrict__ cnt_dst) {
    int e = blockIdx.x * blockDim.x + threadIdx.x;
    if (e < N_EDGES) {
        atomicAdd(&cnt_src[src[e]], 1);
        atomicAdd(&cnt_dst[dst[e]], 1);
    }
}

// norm = clip(deg,1)^-0.5  (use precise 1/sqrtf, not rsqrtf approx)
__global__ void norms_kernel(const int* __restrict__ cnt_src, const int* __restrict__ cnt_dst,
                             float* __restrict__ nsrc, float* __restrict__ ndst) {
    int i = blockIdx.x * blockDim.x + threadIdx.x;
    if (i < N_NODES) {
        nsrc[i] = 1.0f / sqrtf(fmaxf((float)cnt_src[i], 1.0f));
        ndst[i] = 1.0f / sqrtf(fmaxf((float)cnt_dst[i], 1.0f));
    }
}

// --- exclusive scan of cnt_dst -> offs, 3 phases -------------------------
__global__ void scanA_kernel(const int* __restrict__ cnt, int* __restrict__ offs,
                             int* __restrict__ bsum) {
    __shared__ int tmp[256];
    int t = threadIdx.x;
    int gid = blockIdx.x * 256 + t;
    int v = (gid < N_NODES) ? cnt[gid] : 0;
    tmp[t] = v;
    __syncthreads();
    for (int off = 1; off < 256; off <<= 1) {
        int u = (t >= off) ? tmp[t - off] : 0;
        __syncthreads();
        tmp[t] += u;
        __syncthreads();
    }
    if (gid < N_NODES) offs[gid] = tmp[t] - v;        // exclusive within block
    if (t == 255) bsum[blockIdx.x] = tmp[255];        // block total
}

__global__ void scanB_kernel(int* __restrict__ bsum) {
    __shared__ int tmp[256];
    int t = threadIdx.x;
    int v = (t < NB_SCAN) ? bsum[t] : 0;
    tmp[t] = v;
    __syncthreads();
    for (int off = 1; off < 256; off <<= 1) {
        int u = (t >= off) ? tmp[t - off] : 0;
        __syncthreads();
        tmp[t] += u;
        __syncthreads();
    }
    if (t < NB_SCAN) bsum[t] = tmp[t] - v;            // exclusive block offsets
}

__global__ void scanC_kernel(int* __restrict__ offs, const int* __restrict__ bsum,
                             int* __restrict__ cur) {
    int i = blockIdx.x * blockDim.x + threadIdx.x;
    if (i < N_NODES) {
        int o = offs[i] + bsum[i >> 8];
        offs[i] = o;
        cur[i] = o;
    }
    if (i == 0) offs[N_NODES] = N_EDGES;
}

// scatter edges into dst-sorted order (int atomics on cursors only)
__global__ void scatter_kernel(const int* __restrict__ src, const int* __restrict__ dst,
                               int* __restrict__ cur, int* __restrict__ sorted_src) {
    int e = blockIdx.x * blockDim.x + threadIdx.x;
    if (e < N_EDGES) {
        int pos = atomicAdd(&cur[dst[e]], 1);
        sorted_src[pos] = src[e];
    }
}

// ---------------------------------------------------------------------------
// y1 = (x @ W1) * nsrc[:,None].  lane = row (64 rows/wave), W1 rows via
// uniform scalar loads (SGPR operand of v_fmac) -> no LDS, no shuffles.
__global__ void gemm1_kernel(const float* __restrict__ x, const float* __restrict__ W1,
                             const float* __restrict__ nsrc, float* __restrict__ y1) {
    int lane = threadIdx.x & 63;
    int wid = blockIdx.x * (blockDim.x >> 6) + (threadIdx.x >> 6);
    int row = wid * 64 + lane;

    float acc[HID];
    #pragma unroll
    for (int f = 0; f < HID; ++f) acc[f] = 0.0f;

    if (row < N_NODES) {
        #pragma unroll 1
        for (int kc = 0; kc < 4; ++kc) {              // 4 chunks of 32 k's
            float xk[32];
            const float4* xp = reinterpret_cast<const float4*>(x + (size_t)row * IN_F + kc * 32);
            #pragma unroll
            for (int q = 0; q < 8; ++q) {
                float4 tq = xp[q];
                xk[4 * q + 0] = tq.x; xk[4 * q + 1] = tq.y;
                xk[4 * q + 2] = tq.z; xk[4 * q + 3] = tq.w;
            }
            #pragma unroll
            for (int k = 0; k < 32; ++k) {
                const float* wr = W1 + (size_t)(kc * 32 + k) * HID;  // uniform -> s_load
                #pragma unroll
                for (int f = 0; f < HID; ++f)
                    acc[f] = fmaf(xk[k], wr[f], acc[f]);
            }
        }
        float nn = nsrc[row];
        float4* yp = reinterpret_cast<float4*>(y1 + (size_t)row * HID);
        #pragma unroll
        for (int q = 0; q < 16; ++q)
            yp[q] = make_float4(acc[4 * q] * nn, acc[4 * q + 1] * nn,
                                acc[4 * q + 2] * nn, acc[4 * q + 3] * nn);
    }
}

// ---------------------------------------------------------------------------
// Layer-1 tail, gather-based, fused: wave per node, lane = feature.
// agg = sum y1[src]; h = relu(agg*ndst + b1)*drop; s = (h . W2) * nsrc
__global__ void gather1_kernel(const int* __restrict__ offs, const int* __restrict__ sorted_src,
                               const float* __restrict__ y1, const float* __restrict__ ndst,
                               const float* __restrict__ nsrc, const float* __restrict__ b1,
                               const float* __restrict__ drop, const float* __restrict__ W2,
                               float* __restrict__ s) {
    int lane = threadIdx.x & 63;
    int i = blockIdx.x * (blockDim.x >> 6) + (threadIdx.x >> 6);   // node id
    if (i >= N_NODES) return;

    int start = offs[i], end = offs[i + 1];
    float a0 = 0.0f, a1 = 0.0f, a2 = 0.0f, a3 = 0.0f;
    int j = start;
    for (; j + 4 <= end; j += 4) {
        int s0 = sorted_src[j + 0], s1 = sorted_src[j + 1];
        int s2 = sorted_src[j + 2], s3 = sorted_src[j + 3];
        a0 += y1[(size_t)s0 * HID + lane];
        a1 += y1[(size_t)s1 * HID + lane];
        a2 += y1[(size_t)s2 * HID + lane];
        a3 += y1[(size_t)s3 * HID + lane];
    }
    for (; j < end; ++j) a0 += y1[(size_t)sorted_src[j] * HID + lane];
    float acc = (a0 + a1) + (a2 + a3);

    float a = fmaxf(acc * ndst[i] + b1[lane], 0.0f) * drop[(size_t)i * HID + lane];
    float c = a * W2[lane];
    #pragma unroll
    for (int m = 32; m >= 1; m >>= 1) c += __shfl_xor(c, m, 64);
    if (lane == 0) s[i] = c * nsrc[i];
}

// Layer-2 aggregation + sigmoid: wave per node, lane per edge.
__global__ void gather2_kernel(const int* __restrict__ offs, const int* __restrict__ sorted_src,
                               const float* __restrict__ s, const float* __restrict__ ndst,
                               const float* __restrict__ b2, float* __restrict__ out) {
    int lane = threadIdx.x & 63;
    int i = blockIdx.x * (blockDim.x >> 6) + (threadIdx.x >> 6);
    if (i >= N_NODES) return;

    int start = offs[i], end = offs[i + 1];
    float c = 0.0f;
    for (int j = start + lane; j < end; j += 64) c += s[sorted_src[j]];
    #pragma unroll
    for (int m = 32; m >= 1; m >>= 1) c += __shfl_xor(c, m, 64);
    if (lane == 0) {
        float v = c * ndst[i] + b2[0];
        out[i] = 1.0f / (1.0f + expf(-v));
    }
}

// ---------------------------------------------------------------------------
extern "C" void kernel_launch(void* const* d_in, const int* in_sizes, int n_in,
                              void* d_out, int out_size, void* d_ws, size_t ws_size,
                              hipStream_t stream) {
    const float* x    = (const float*)d_in[0];
    const float* W1   = (const float*)d_in[1];
    const float* b1   = (const float*)d_in[2];
    const float* W2   = (const float*)d_in[3];
    const float* b2   = (const float*)d_in[4];
    const int*   src  = (const int*)d_in[5];
    const int*   dst  = (const int*)d_in[6];
    const float* drop = (const float*)d_in[7];
    float* out = (float*)d_out;

    // Workspace layout (~17.5 MB)
    float* y1         = (float*)d_ws;                        // 64N floats
    int*   sorted_src = (int*)(y1 + (size_t)HID * N_NODES);  // E
    int*   offs       = sorted_src + N_EDGES;                // N+1
    int*   cur        = offs + N_NODES + 1;                  // N
    int*   cnt_src    = cur + N_NODES;                       // N
    int*   cnt_dst    = cnt_src + N_NODES;                   // N  (contiguous with cnt_src)
    int*   bsum       = cnt_dst + N_NODES;                   // 256
    float* nsrc       = (float*)(bsum + 256);                // N
    float* ndst       = nsrc + N_NODES;                      // N
    float* s          = ndst + N_NODES;                      // N

    hipMemsetAsync(cnt_src, 0, (size_t)2 * N_NODES * sizeof(int), stream);

    int eb = (N_EDGES + 255) / 256;   // 3125
    int nb = NB_SCAN;                 // 196

    hist_kernel   <<<eb, 256, 0, stream>>>(src, dst, cnt_src, cnt_dst);
    norms_kernel  <<<nb, 256, 0, stream>>>(cnt_src, cnt_dst, nsrc, ndst);
    gemm1_kernel  <<<nb, 256, 0, stream>>>(x, W1, nsrc, y1);
    scanA_kernel  <<<nb, 256, 0, stream>>>(cnt_dst, offs, bsum);
    scanB_kernel  <<<1, 256, 0, stream>>>(bsum);
    scanC_kernel  <<<nb, 256, 0, stream>>>(offs, bsum, cur);
    scatter_kernel<<<eb, 256, 0, stream>>>(src, dst, cur, sorted_src);
    gather1_kernel<<<(N_NODES + 3) / 4, 256, 0, stream>>>(offs, sorted_src, y1, ndst, nsrc, b1, drop, W2, s);
    gather2_kernel<<<(N_NODES + 3) / 4, 256, 0, stream>>>(offs, sorted_src, s, ndst, b2, out);
}